// Round 4
// baseline (134.104 us; speedup 1.0000x reference)
//
#include <hip/hip_runtime.h>
#include <math.h>

#define D_MODEL 512
#define N_HEADS 8
#define DH      64
#define S_LEN   3072
#define BATCH   2
#define KMAX    32
#define M_ROWS  (BATCH * S_LEN)   // 6144
#define CAND_CAP 512

typedef __attribute__((ext_vector_type(8))) short bf16x8;
typedef __attribute__((ext_vector_type(4))) float f32x4;

__device__ __forceinline__ float b2f(unsigned int u) {
    return __uint_as_float((u & 0xFFFFu) << 16);
}
__device__ __forceinline__ unsigned short f2b(float f) {
    unsigned int u = __float_as_uint(f);
    return (unsigned short)((u + 0x7FFFu + ((u >> 16) & 1u)) >> 16);  // RNE
}

// ---------------------------------------------------------------------------
// x (fp32, M x 512) -> bf16
// ---------------------------------------------------------------------------
__global__ __launch_bounds__(256) void conv_x_kernel(
    const float* __restrict__ x, unsigned short* __restrict__ xb)
{
    const int i = (blockIdx.x * 256 + threadIdx.x) * 4;
    const float4 v = *reinterpret_cast<const float4*>(x + i);
    ushort4 o;
    o.x = f2b(v.x); o.y = f2b(v.y); o.z = f2b(v.z); o.w = f2b(v.w);
    *reinterpret_cast<ushort4*>(xb + i) = o;
}

// ---------------------------------------------------------------------------
// Pack weights: Wt[n][k] = W*[k][n'] as bf16, n = 0..2047
//   [0,512) Wq | [512,1024) Wk | [1024,1536) Wv | [1536,2048) Wo
// ---------------------------------------------------------------------------
__global__ __launch_bounds__(256) void pack_w_kernel(
    const float* __restrict__ Wq, const float* __restrict__ bq,
    const float* __restrict__ Wk, const float* __restrict__ bk,
    const float* __restrict__ Wv, const float* __restrict__ bv,
    const float* __restrict__ Wo,
    unsigned short* __restrict__ Wt, float* __restrict__ bqkv)
{
    const int n = blockIdx.x;
    const float* W; int nn;
    if (n < 512)       { W = Wq; nn = n; }
    else if (n < 1024) { W = Wk; nn = n - 512; }
    else if (n < 1536) { W = Wv; nn = n - 1024; }
    else               { W = Wo; nn = n - 1536; }
    for (int k = threadIdx.x; k < 512; k += 256)
        Wt[(size_t)n * 512 + k] = f2b(W[(size_t)k * 512 + nn]);
    if (threadIdx.x == 0 && n < 1536) {
        const float* bsel = (n < 512) ? bq : (n < 1024) ? bk : bv;
        bqkv[n] = bsel[nn];
    }
}

// ---------------------------------------------------------------------------
// bf16 MFMA GEMM, 128x128 tile, 4 waves, BK=32, global_load_lds staging.
// MODE 0: QKV epilogue -> Qb [m][512] bf16, Kb/Vb [b][h][s][64] bf16.
// MODE 1: fp32 C -> C0 [m][512], ldc=512.
// ---------------------------------------------------------------------------
template <int MODE>
__global__ __launch_bounds__(256) void gemm_mfma_kernel(
    const unsigned short* __restrict__ A,
    const unsigned short* __restrict__ Bt,
    const float* __restrict__ bias,
    void* __restrict__ C0, void* __restrict__ C1, void* __restrict__ C2)
{
    constexpr int K = 512;
    __shared__ __align__(16) unsigned short As[128 * 32];
    __shared__ __align__(16) unsigned short Bs[128 * 32];

    const int tid = threadIdx.x;
    const int m0 = blockIdx.x * 128;
    const int n0 = blockIdx.y * 128;
    const int wid = tid >> 6;
    const int lane = tid & 63;
    const int wm = (wid >> 1) * 64;
    const int wn = (wid & 1) * 64;
    const int l15 = lane & 15;
    const int kg = lane >> 4;

    const int srow = tid >> 2;
    const int sk = (tid & 3) * 8;

    f32x4 acc[4][4] = {};

    for (int kt = 0; kt < K; kt += 32) {
        #pragma unroll
        for (int c = 0; c < 2; ++c) {
            const unsigned short* ga = A + (size_t)(m0 + c * 64 + srow) * K + kt + sk;
            __builtin_amdgcn_global_load_lds(
                (const __attribute__((address_space(1))) void*)ga,
                (__attribute__((address_space(3))) void*)(&As[c * 2048 + tid * 8]),
                16, 0, 0);
            const unsigned short* gb = Bt + (size_t)(n0 + c * 64 + srow) * K + kt + sk;
            __builtin_amdgcn_global_load_lds(
                (const __attribute__((address_space(1))) void*)gb,
                (__attribute__((address_space(3))) void*)(&Bs[c * 2048 + tid * 8]),
                16, 0, 0);
        }
        __syncthreads();

        bf16x8 af[4], bfr[4];
        #pragma unroll
        for (int i = 0; i < 4; ++i) {
            af[i]  = *reinterpret_cast<const bf16x8*>(&As[(wm + i * 16 + l15) * 32 + kg * 8]);
            bfr[i] = *reinterpret_cast<const bf16x8*>(&Bs[(wn + i * 16 + l15) * 32 + kg * 8]);
        }
        #pragma unroll
        for (int i = 0; i < 4; ++i)
            #pragma unroll
            for (int j = 0; j < 4; ++j)
                acc[i][j] = __builtin_amdgcn_mfma_f32_16x16x32_bf16(af[i], bfr[j], acc[i][j], 0, 0, 0);
        __syncthreads();
    }

    // C/D layout: col = lane&15, row = (lane>>4)*4 + reg
    const int crow = kg * 4;
    #pragma unroll
    for (int i = 0; i < 4; ++i) {
        #pragma unroll
        for (int j = 0; j < 4; ++j) {
            const int col = n0 + wn + j * 16 + l15;
            const float bb = bias[col];
            #pragma unroll
            for (int r = 0; r < 4; ++r) {
                const int row = m0 + wm + i * 16 + crow + r;
                const float v = acc[i][j][r] + bb;
                if (MODE == 1) {
                    ((float*)C0)[(size_t)row * 512 + col] = v;
                } else {
                    if (col < 512) {
                        ((unsigned short*)C0)[(size_t)row * 512 + col] = f2b(v);
                    } else {
                        const int part = (col >= 1024) ? 1 : 0;
                        const int cc = col - 512 - (part << 9);
                        const int hh = cc >> 6;
                        const int dd = cc & 63;
                        const int bb2 = (row >= S_LEN) ? 1 : 0;
                        const int ss = row - bb2 * S_LEN;
                        unsigned short* dst = (unsigned short*)(part ? C2 : C1);
                        dst[((size_t)(bb2 * N_HEADS + hh) * S_LEN + ss) * DH + dd] = f2b(v);
                    }
                }
            }
        }
    }
}

// ---------------------------------------------------------------------------
// Top-k neighbor selection (rank-based), one 256-thread block per row.
// ---------------------------------------------------------------------------
__global__ __launch_bounds__(256) void topk_kernel(
    const float* __restrict__ pos,
    int* __restrict__ nbr_idx,
    int* __restrict__ nbr_cnt)
{
    const int row = blockIdx.x;
    const int b = row / S_LEN;
    const int tid = threadIdx.x;

    __shared__ unsigned long long s_keys[CAND_CAP];
    __shared__ int s_n;

    if (tid == 0) s_n = 0;
    __syncthreads();

    const float px = pos[(long)row * 3 + 0];
    const float py = pos[(long)row * 3 + 1];
    const float pz = pos[(long)row * 3 + 2];
    const float* pb = pos + (long)b * S_LEN * 3;

    #pragma unroll
    for (int i = 0; i < 12; ++i) {
        const int t = tid + i * 256;
        const float dx = px - pb[t * 3 + 0];
        const float dy = py - pb[t * 3 + 1];
        const float dz = pz - pb[t * 3 + 2];
        const float dist = sqrtf(dx * dx + dy * dy + dz * dz);
        if (dist < 0.5f) {
            const int slot = atomicAdd(&s_n, 1);
            if (slot < CAND_CAP)
                s_keys[slot] = (((unsigned long long)__float_as_uint(dist)) << 32)
                               | (unsigned int)t;
        }
    }
    __syncthreads();

    const int n = (s_n < CAND_CAP) ? s_n : CAND_CAP;

    for (int c = tid; c < n; c += 256) {
        const unsigned long long mykey = s_keys[c];
        int rank = 0;
        for (int j = 0; j < n; ++j)
            rank += (s_keys[j] < mykey) ? 1 : 0;
        if (rank < KMAX)
            nbr_idx[(long)row * KMAX + rank] = (int)(mykey & 0xFFFFFFFFu);
    }
    if (tid == 0) nbr_cnt[row] = (n < KMAX) ? n : KMAX;
}

// ---------------------------------------------------------------------------
// Sparse attention: one wave per (row, head). No LDS, no barriers.
// Qb: [m][512] bf16. Kb/Vb: [b][h][s][64] bf16. ao: [m][512] bf16.
// Lanes 0..31 and 32..63 duplicate the score work (j = lane&31); all 64
// lanes participate in PV (d = lane).
// ---------------------------------------------------------------------------
__global__ __launch_bounds__(256) void attn_kernel(
    const unsigned short* __restrict__ Qb,
    const unsigned short* __restrict__ Kb,
    const unsigned short* __restrict__ Vb,
    const int* __restrict__ nbr_idx,
    const int* __restrict__ nbr_cnt,
    unsigned short* __restrict__ ao)
{
    const int lane = threadIdx.x & 63;
    const int wid = __builtin_amdgcn_readfirstlane(threadIdx.x >> 6);
    const int gw = blockIdx.x * 4 + wid;       // wave-uniform
    const int row = gw >> 3;
    const int h = gw & 7;
    const int b = (row >= S_LEN) ? 1 : 0;
    const int j = lane & 31;

    const int cnt = nbr_cnt[row];                       // uniform -> s_load
    const int* nrow = nbr_idx + (size_t)row * KMAX;     // uniform base

    const unsigned short* kh = Kb + (size_t)(b * N_HEADS + h) * S_LEN * DH;
    const unsigned short* vh = Vb + (size_t)(b * N_HEADS + h) * S_LEN * DH;
    const unsigned int* qw = (const unsigned int*)(Qb + (size_t)row * D_MODEL + h * DH);

    // --- K gather: lane j loads the full 64-dim K row of neighbor j ---
    const int tj_raw = nrow[j];                         // per-lane vector load
    const int tj = (j < cnt) ? tj_raw : 0;              // clamp (garbage slots)
    uint4 ku[8];
    {
        const uint4* kp = reinterpret_cast<const uint4*>(kh + (size_t)tj * DH);
        #pragma unroll
        for (int c = 0; c < 8; ++c) ku[c] = kp[c];
    }

    // --- V prefetch: lane d holds V[t_j][d] for every j (scalar addresses) ---
    unsigned short vr[KMAX];
    #pragma unroll
    for (int jj = 0; jj < KMAX; ++jj) {
        const int t_s = (jj < cnt) ? nrow[jj] : 0;      // uniform -> s_load
        vr[jj] = vh[(size_t)t_s * DH + lane];
    }

    // --- score: 64-dim dot, Q from (scalar) packed words ---
    float partial = 0.f;
    #pragma unroll
    for (int c = 0; c < 8; ++c) {
        const unsigned int q0 = qw[c * 4 + 0];
        const unsigned int q1 = qw[c * 4 + 1];
        const unsigned int q2 = qw[c * 4 + 2];
        const unsigned int q3 = qw[c * 4 + 3];
        partial += b2f(q0)       * b2f(ku[c].x) + b2f(q0 >> 16) * b2f(ku[c].x >> 16)
                 + b2f(q1)       * b2f(ku[c].y) + b2f(q1 >> 16) * b2f(ku[c].y >> 16)
                 + b2f(q2)       * b2f(ku[c].z) + b2f(q2 >> 16) * b2f(ku[c].z >> 16)
                 + b2f(q3)       * b2f(ku[c].w) + b2f(q3 >> 16) * b2f(ku[c].w >> 16);
    }

    // --- softmax over 32 neighbor slots (both wave halves hold copies) ---
    const float sc = (j < cnt) ? partial * 0.125f : -INFINITY;
    float mx = sc;
    #pragma unroll
    for (int off = 16; off; off >>= 1) mx = fmaxf(mx, __shfl_xor(mx, off, 64));
    const float p = (j < cnt) ? expf(sc - mx) : 0.f;
    float sum = p;
    #pragma unroll
    for (int off = 16; off; off >>= 1) sum += __shfl_xor(sum, off, 64);
    const float inv = 1.f / sum;   // valid in every lane (halves identical)

    // --- PV: o[d] = sum_j w_j * V[t_j][d], weights broadcast via readlane ---
    float o = 0.f;
    #pragma unroll
    for (int jj = 0; jj < KMAX; ++jj) {
        const float w = __uint_as_float(
            __builtin_amdgcn_readlane(__float_as_uint(p), jj));
        o += w * b2f(vr[jj]);
    }
    o *= inv;
    ao[(size_t)row * D_MODEL + h * DH + lane] = f2b(o);
}

// ---------------------------------------------------------------------------
extern "C" void kernel_launch(void* const* d_in, const int* in_sizes, int n_in,
                              void* d_out, int out_size, void* d_ws, size_t ws_size,
                              hipStream_t stream) {
    const float* x   = (const float*)d_in[0];
    const float* pos = (const float*)d_in[1];
    const float* Wq  = (const float*)d_in[2];
    const float* bq  = (const float*)d_in[3];
    const float* Wk  = (const float*)d_in[4];
    const float* bk  = (const float*)d_in[5];
    const float* Wv  = (const float*)d_in[6];
    const float* bv  = (const float*)d_in[7];
    const float* Wo  = (const float*)d_in[8];
    const float* bo  = (const float*)d_in[9];
    float* out = (float*)d_out;

    // workspace layout (all 16B-aligned)
    unsigned short* xb   = (unsigned short*)d_ws;                 // 6144*512
    unsigned short* Wt   = xb + (size_t)M_ROWS * 512;             // 2048*512
    float*          bqkv = (float*)(Wt + (size_t)2048 * 512);     // 1536
    unsigned short* Qb   = (unsigned short*)(bqkv + 1536);        // 6144*512
    unsigned short* Kb   = Qb + (size_t)M_ROWS * 512;             // 2*8*3072*64
    unsigned short* Vb   = Kb + (size_t)M_ROWS * 512;             // 2*8*3072*64
    unsigned short* aob  = Vb + (size_t)M_ROWS * 512;             // 6144*512
    int*            nidx = (int*)(aob + (size_t)M_ROWS * 512);    // 6144*32
    int*            ncnt = nidx + (size_t)M_ROWS * KMAX;          // 6144

    conv_x_kernel<<<M_ROWS * D_MODEL / (256 * 4), 256, 0, stream>>>(x, xb);
    pack_w_kernel<<<2048, 256, 0, stream>>>(Wq, bq, Wk, bk, Wv, bv, Wo, Wt, bqkv);
    topk_kernel<<<M_ROWS, 256, 0, stream>>>(pos, nidx, ncnt);

    dim3 g1(M_ROWS / 128, 1536 / 128);
    gemm_mfma_kernel<0><<<g1, 256, 0, stream>>>(xb, Wt, bqkv, Qb, Kb, Vb);

    attn_kernel<<<M_ROWS * N_HEADS / 4, 256, 0, stream>>>(Qb, Kb, Vb, nidx, ncnt, aob);

    dim3 g2(M_ROWS / 128, 512 / 128);
    gemm_mfma_kernel<1><<<g2, 256, 0, stream>>>(aob, Wt + (size_t)1536 * 512, bo, out, nullptr, nullptr);
}

// Round 5
// 112.880 us; speedup vs baseline: 1.1880x; 1.1880x over previous
//
#include <hip/hip_runtime.h>
#include <math.h>

#define D_MODEL 512
#define N_HEADS 8
#define DH      64
#define S_LEN   3072
#define BATCH   2
#define KMAX    32
#define M_ROWS  (BATCH * S_LEN)   // 6144
#define CAND_CAP 512

typedef __attribute__((ext_vector_type(8))) short bf16x8;
typedef __attribute__((ext_vector_type(4))) float f32x4;

__device__ __forceinline__ float b2f(unsigned int u) {
    return __uint_as_float((u & 0xFFFFu) << 16);
}
__device__ __forceinline__ unsigned short f2b(float f) {
    unsigned int u = __float_as_uint(f);
    return (unsigned short)((u + 0x7FFFu + ((u >> 16) & 1u)) >> 16);  // RNE
}

// ---------------------------------------------------------------------------
// x (fp32, M x 512) -> bf16
// ---------------------------------------------------------------------------
__global__ __launch_bounds__(256) void conv_x_kernel(
    const float* __restrict__ x, unsigned short* __restrict__ xb)
{
    const int i = (blockIdx.x * 256 + threadIdx.x) * 4;
    const float4 v = *reinterpret_cast<const float4*>(x + i);
    ushort4 o;
    o.x = f2b(v.x); o.y = f2b(v.y); o.z = f2b(v.z); o.w = f2b(v.w);
    *reinterpret_cast<ushort4*>(xb + i) = o;
}

// ---------------------------------------------------------------------------
// Pack weights: Wt[n][k] = W*[k][n'] as bf16, n = 0..2047
//   [0,512) Wq | [512,1024) Wk | [1024,1536) Wv | [1536,2048) Wo
// ---------------------------------------------------------------------------
__global__ __launch_bounds__(256) void pack_w_kernel(
    const float* __restrict__ Wq, const float* __restrict__ bq,
    const float* __restrict__ Wk, const float* __restrict__ bk,
    const float* __restrict__ Wv, const float* __restrict__ bv,
    const float* __restrict__ Wo,
    unsigned short* __restrict__ Wt, float* __restrict__ bqkv)
{
    const int n = blockIdx.x;
    const float* W; int nn;
    if (n < 512)       { W = Wq; nn = n; }
    else if (n < 1024) { W = Wk; nn = n - 512; }
    else if (n < 1536) { W = Wv; nn = n - 1024; }
    else               { W = Wo; nn = n - 1536; }
    for (int k = threadIdx.x; k < 512; k += 256)
        Wt[(size_t)n * 512 + k] = f2b(W[(size_t)k * 512 + nn]);
    if (threadIdx.x == 0 && n < 1536) {
        const float* bsel = (n < 512) ? bq : (n < 1024) ? bk : bv;
        bqkv[n] = bsel[nn];
    }
}

// ---------------------------------------------------------------------------
// bf16 MFMA GEMM: C[m][n] = sum_k A[m][k] * Bt[n][k] + bias[n]
// 128x128 tile, 256 threads (4 waves 2x2, each 64x64), BK=32,
// global_load_lds width-16 staging, mfma_f32_16x16x32_bf16.
// ---------------------------------------------------------------------------
template <bool OUT_BF16>
__global__ __launch_bounds__(256) void gemm_mfma_kernel(
    const unsigned short* __restrict__ A,
    const unsigned short* __restrict__ Bt,
    const float* __restrict__ bias,
    void* __restrict__ Cv, int ldc, int c_off)
{
    constexpr int K = 512;
    __shared__ __align__(16) unsigned short As[128 * 32];
    __shared__ __align__(16) unsigned short Bs[128 * 32];

    const int tid = threadIdx.x;
    const int m0 = blockIdx.x * 128;
    const int n0 = blockIdx.y * 128;
    const int wid = tid >> 6;
    const int lane = tid & 63;
    const int wm = (wid >> 1) * 64;
    const int wn = (wid & 1) * 64;
    const int l15 = lane & 15;
    const int kg = lane >> 4;

    const int srow = tid >> 2;
    const int sk = (tid & 3) * 8;

    f32x4 acc[4][4] = {};

    for (int kt = 0; kt < K; kt += 32) {
        #pragma unroll
        for (int c = 0; c < 2; ++c) {
            const unsigned short* ga = A + (size_t)(m0 + c * 64 + srow) * K + kt + sk;
            __builtin_amdgcn_global_load_lds(
                (const __attribute__((address_space(1))) void*)ga,
                (__attribute__((address_space(3))) void*)(&As[c * 2048 + tid * 8]),
                16, 0, 0);
            const unsigned short* gb = Bt + (size_t)(n0 + c * 64 + srow) * K + kt + sk;
            __builtin_amdgcn_global_load_lds(
                (const __attribute__((address_space(1))) void*)gb,
                (__attribute__((address_space(3))) void*)(&Bs[c * 2048 + tid * 8]),
                16, 0, 0);
        }
        __syncthreads();

        bf16x8 af[4], bfr[4];
        #pragma unroll
        for (int i = 0; i < 4; ++i) {
            af[i]  = *reinterpret_cast<const bf16x8*>(&As[(wm + i * 16 + l15) * 32 + kg * 8]);
            bfr[i] = *reinterpret_cast<const bf16x8*>(&Bs[(wn + i * 16 + l15) * 32 + kg * 8]);
        }
        #pragma unroll
        for (int i = 0; i < 4; ++i)
            #pragma unroll
            for (int j = 0; j < 4; ++j)
                acc[i][j] = __builtin_amdgcn_mfma_f32_16x16x32_bf16(af[i], bfr[j], acc[i][j], 0, 0, 0);
        __syncthreads();
    }

    // C/D layout (m89-verified): col = lane&15, row = (lane>>4)*4 + reg
    const int crow = kg * 4;
    #pragma unroll
    for (int i = 0; i < 4; ++i) {
        #pragma unroll
        for (int j = 0; j < 4; ++j) {
            const int col = n0 + wn + j * 16 + l15;
            const float bb = bias[col];
            #pragma unroll
            for (int r = 0; r < 4; ++r) {
                const int row = m0 + wm + i * 16 + crow + r;
                const float v = acc[i][j][r] + bb;
                if (OUT_BF16)
                    ((unsigned short*)Cv)[(size_t)row * ldc + c_off + col] = f2b(v);
                else
                    ((float*)Cv)[(size_t)row * ldc + c_off + col] = v;
            }
        }
    }
}

// ---------------------------------------------------------------------------
// Top-k neighbor selection (rank-based), one 256-thread block per row.
// ---------------------------------------------------------------------------
__global__ __launch_bounds__(256) void topk_kernel(
    const float* __restrict__ pos,
    int* __restrict__ nbr_idx,
    int* __restrict__ nbr_cnt)
{
    const int row = blockIdx.x;
    const int b = row / S_LEN;
    const int tid = threadIdx.x;

    __shared__ unsigned long long s_keys[CAND_CAP];
    __shared__ int s_n;

    if (tid == 0) s_n = 0;
    __syncthreads();

    const float px = pos[(long)row * 3 + 0];
    const float py = pos[(long)row * 3 + 1];
    const float pz = pos[(long)row * 3 + 2];
    const float* pb = pos + (long)b * S_LEN * 3;

    #pragma unroll
    for (int i = 0; i < 12; ++i) {
        const int t = tid + i * 256;
        const float dx = px - pb[t * 3 + 0];
        const float dy = py - pb[t * 3 + 1];
        const float dz = pz - pb[t * 3 + 2];
        const float dist = sqrtf(dx * dx + dy * dy + dz * dz);
        if (dist < 0.5f) {
            const int slot = atomicAdd(&s_n, 1);
            if (slot < CAND_CAP)
                s_keys[slot] = (((unsigned long long)__float_as_uint(dist)) << 32)
                               | (unsigned int)t;
        }
    }
    __syncthreads();

    const int n = (s_n < CAND_CAP) ? s_n : CAND_CAP;

    for (int c = tid; c < n; c += 256) {
        const unsigned long long mykey = s_keys[c];
        int rank = 0;
        for (int j = 0; j < n; ++j)
            rank += (s_keys[j] < mykey) ? 1 : 0;
        if (rank < KMAX)
            nbr_idx[(long)row * KMAX + rank] = (int)(mykey & 0xFFFFFFFFu);
    }
    if (tid == 0) nbr_cnt[row] = (n < KMAX) ? n : KMAX;
}

// ---------------------------------------------------------------------------
// Sparse attention. One 512-thread block per (b, s); wave h handles head h.
// qkv: [M][1536] bf16 = [Q512 | K512 | V512].
// Single barrier; V prefetched into registers (issued after K loads so the
// score's vmcnt wait keeps V in flight); softmax weights broadcast in-wave
// via readlane (no sW LDS, no 2nd barrier).
// ---------------------------------------------------------------------------
__global__ __launch_bounds__(512) void attn_kernel(
    const unsigned short* __restrict__ qkv,
    const int* __restrict__ nbr_idx,
    const int* __restrict__ nbr_cnt,
    unsigned short* __restrict__ ao)
{
    const int row = blockIdx.x;
    const int b = row / S_LEN;
    const int tid = threadIdx.x;
    const int h = tid >> 6;
    const int lane = tid & 63;

    __shared__ int s_nbr[KMAX];
    __shared__ int s_cnt;
    __shared__ float sQ[N_HEADS][DH];

    if (tid < KMAX) s_nbr[tid] = nbr_idx[(size_t)row * KMAX + tid];
    if (tid == 0) s_cnt = nbr_cnt[row];
    sQ[h][lane] = b2f(qkv[(size_t)row * 1536 + tid]);
    __syncthreads();
    const int cnt = s_cnt;

    // --- K gather (issued first): lane pair (j, j+32) splits the 64-dim dot ---
    const int j = lane & 31;
    const int half = lane >> 5;
    const int tj = (j < cnt) ? s_nbr[j] : 0;
    uint4 ku[4];
    {
        const uint4* kp = reinterpret_cast<const uint4*>(
            qkv + (size_t)(b * S_LEN + tj) * 1536 + 512 + h * DH + half * 32);
        #pragma unroll
        for (int c = 0; c < 4; ++c) ku[c] = kp[c];
    }

    // --- V register prefetch (issued after K; stays in flight through score) ---
    const unsigned short* vbase = qkv + 1024 + h * DH + lane;
    unsigned short vr[KMAX];
    #pragma unroll
    for (int jj = 0; jj < KMAX; ++jj) {
        const int t = (jj < cnt) ? s_nbr[jj] : 0;
        vr[jj] = vbase[(size_t)(b * S_LEN + t) * 1536];
    }

    // --- score: 64-dim dot split across lane halves ---
    const float* qp = &sQ[h][half * 32];
    float partial = 0.f;
    #pragma unroll
    for (int c = 0; c < 4; ++c) {
        const int d0 = c * 8;
        partial += qp[d0 + 0] * b2f(ku[c].x) + qp[d0 + 1] * b2f(ku[c].x >> 16)
                 + qp[d0 + 2] * b2f(ku[c].y) + qp[d0 + 3] * b2f(ku[c].y >> 16)
                 + qp[d0 + 4] * b2f(ku[c].z) + qp[d0 + 5] * b2f(ku[c].z >> 16)
                 + qp[d0 + 6] * b2f(ku[c].w) + qp[d0 + 7] * b2f(ku[c].w >> 16);
    }
    partial += __shfl_down(partial, 32, 64);   // lanes 0..31 hold full dots

    // --- softmax over lanes 0..31 ---
    const float sc = (half == 0 && j < cnt) ? partial * 0.125f : -INFINITY;
    float mx = sc;
    #pragma unroll
    for (int off = 16; off; off >>= 1) mx = fmaxf(mx, __shfl_xor(mx, off, 64));
    const float p = (half == 0 && j < cnt) ? expf(sc - mx) : 0.f;
    float sum = p;
    #pragma unroll
    for (int off = 16; off; off >>= 1) sum += __shfl_xor(sum, off, 64);
    const float inv = __uint_as_float(
        __builtin_amdgcn_readfirstlane(__float_as_uint(1.f / sum)));

    // --- PV from registers: weights broadcast via readlane, 4 accumulators ---
    float o0 = 0.f, o1 = 0.f, o2 = 0.f, o3 = 0.f;
    #pragma unroll
    for (int jj = 0; jj < KMAX; jj += 4) {
        const float w0 = __uint_as_float(__builtin_amdgcn_readlane(__float_as_uint(p), jj));
        const float w1 = __uint_as_float(__builtin_amdgcn_readlane(__float_as_uint(p), jj + 1));
        const float w2 = __uint_as_float(__builtin_amdgcn_readlane(__float_as_uint(p), jj + 2));
        const float w3 = __uint_as_float(__builtin_amdgcn_readlane(__float_as_uint(p), jj + 3));
        o0 += w0 * b2f(vr[jj]);
        o1 += w1 * b2f(vr[jj + 1]);
        o2 += w2 * b2f(vr[jj + 2]);
        o3 += w3 * b2f(vr[jj + 3]);
    }
    const float o = ((o0 + o1) + (o2 + o3)) * inv;
    ao[(size_t)row * D_MODEL + tid] = f2b(o);
}

// ---------------------------------------------------------------------------
extern "C" void kernel_launch(void* const* d_in, const int* in_sizes, int n_in,
                              void* d_out, int out_size, void* d_ws, size_t ws_size,
                              hipStream_t stream) {
    const float* x   = (const float*)d_in[0];
    const float* pos = (const float*)d_in[1];
    const float* Wq  = (const float*)d_in[2];
    const float* bq  = (const float*)d_in[3];
    const float* Wk  = (const float*)d_in[4];
    const float* bk  = (const float*)d_in[5];
    const float* Wv  = (const float*)d_in[6];
    const float* bv  = (const float*)d_in[7];
    const float* Wo  = (const float*)d_in[8];
    const float* bo  = (const float*)d_in[9];
    float* out = (float*)d_out;

    // workspace layout (all 16B-aligned)
    unsigned short* xb   = (unsigned short*)d_ws;                 // 6144*512
    unsigned short* Wt   = xb + (size_t)M_ROWS * 512;             // 2048*512
    float*          bqkv = (float*)(Wt + (size_t)2048 * 512);     // 1536
    unsigned short* qkvb = (unsigned short*)(bqkv + 1536);        // 6144*1536
    unsigned short* aob  = qkvb + (size_t)M_ROWS * 1536;          // 6144*512
    int*            nidx = (int*)(aob + (size_t)M_ROWS * 512);    // 6144*32
    int*            ncnt = nidx + (size_t)M_ROWS * KMAX;          // 6144

    conv_x_kernel<<<M_ROWS * D_MODEL / (256 * 4), 256, 0, stream>>>(x, xb);
    pack_w_kernel<<<2048, 256, 0, stream>>>(Wq, bq, Wk, bk, Wv, bv, Wo, Wt, bqkv);
    topk_kernel<<<M_ROWS, 256, 0, stream>>>(pos, nidx, ncnt);

    dim3 g1(M_ROWS / 128, 1536 / 128);
    gemm_mfma_kernel<true><<<g1, 256, 0, stream>>>(xb, Wt, bqkv, qkvb, 1536, 0);

    attn_kernel<<<M_ROWS, 512, 0, stream>>>(qkvb, nidx, ncnt, aob);

    dim3 g2(M_ROWS / 128, 512 / 128);
    gemm_mfma_kernel<false><<<g2, 256, 0, stream>>>(aob, Wt + (size_t)1536 * 512, bo, out, 512, 0);
}

// Round 6
// 101.525 us; speedup vs baseline: 1.3209x; 1.1118x over previous
//
#include <hip/hip_runtime.h>
#include <math.h>

#define D_MODEL 512
#define N_HEADS 8
#define DH      64
#define S_LEN   3072
#define BATCH   2
#define KMAX    32
#define M_ROWS  6144
#define CAND_CAP 512

#define TOPK_BLOCKS (M_ROWS / 4)                 // 1536 (4 rows per block)
#define CONV_BLOCKS (M_ROWS * D_MODEL / 1024)    // 3072
#define PACK_BLOCKS 2048

typedef __attribute__((ext_vector_type(8))) short bf16x8;
typedef __attribute__((ext_vector_type(4))) float f32x4;
typedef unsigned long long u64;

__device__ __forceinline__ float b2f(unsigned int u) {
    return __uint_as_float((u & 0xFFFFu) << 16);
}
__device__ __forceinline__ unsigned short f2b(float f) {
    unsigned int u = __float_as_uint(f);
    return (unsigned short)((u + 0x7FFFu + ((u >> 16) & 1u)) >> 16);  // RNE
}

// ---------------------------------------------------------------------------
// prep: fused topk (4 rows/block) | x->bf16 | weight transpose+pack.
// All three depend only on kernel inputs -> one dispatch, machine overlaps.
// ---------------------------------------------------------------------------
__global__ __launch_bounds__(256) void prep_kernel(
    const float* __restrict__ x, const float* __restrict__ pos,
    const float* __restrict__ Wq, const float* __restrict__ bq,
    const float* __restrict__ Wk, const float* __restrict__ bk,
    const float* __restrict__ Wv, const float* __restrict__ bv,
    const float* __restrict__ Wo,
    unsigned short* __restrict__ xb, unsigned short* __restrict__ Wt,
    float* __restrict__ bqkv,
    int* __restrict__ nbr_idx, int* __restrict__ nbr_cnt)
{
    const int bid = blockIdx.x;
    const int tid = threadIdx.x;

    if (bid < TOPK_BLOCKS) {
        // ---- topk: rows r0..r0+3 (same batch since S_LEN%4==0) ----
        // keys on d^2 (monotonic in dist; same radius & tie-break semantics
        // up to sub-ulp sqrt-rounding boundaries).
        __shared__ u64 s_keys[4][CAND_CAP];
        __shared__ int s_n[4];
        const int r0 = bid * 4;
        const int b = (r0 >= S_LEN) ? 1 : 0;
        if (tid < 4) s_n[tid] = 0;
        __syncthreads();

        float qx[4], qy[4], qz[4];
        #pragma unroll
        for (int r = 0; r < 4; ++r) {
            qx[r] = pos[(size_t)(r0 + r) * 3 + 0];
            qy[r] = pos[(size_t)(r0 + r) * 3 + 1];
            qz[r] = pos[(size_t)(r0 + r) * 3 + 2];
        }
        const float* pb = pos + (size_t)b * S_LEN * 3;
        #pragma unroll
        for (int i = 0; i < 12; ++i) {
            const int t = tid + i * 256;
            const float x3 = pb[t * 3 + 0], y3 = pb[t * 3 + 1], z3 = pb[t * 3 + 2];
            #pragma unroll
            for (int r = 0; r < 4; ++r) {
                const float dx = qx[r] - x3, dy = qy[r] - y3, dz = qz[r] - z3;
                const float d2 = dx * dx + dy * dy + dz * dz;
                if (d2 < 0.25f) {
                    const int slot = atomicAdd(&s_n[r], 1);
                    if (slot < CAND_CAP)
                        s_keys[r][slot] = ((u64)__float_as_uint(d2) << 32) | (unsigned)t;
                }
            }
        }
        __syncthreads();

        // rank selection: wave rr handles row rr
        const int rr = tid >> 6, c0 = tid & 63;
        const int n = min(s_n[rr], CAND_CAP);
        for (int c = c0; c < n; c += 64) {
            const u64 k = s_keys[rr][c];
            int rank = 0;
            for (int j = 0; j < n; ++j) rank += (s_keys[rr][j] < k) ? 1 : 0;
            if (rank < KMAX)
                nbr_idx[(size_t)(r0 + rr) * KMAX + rank] = (int)(k & 0xFFFFFFFFu);
        }
        if (c0 == 0) nbr_cnt[r0 + rr] = min(n, KMAX);
    } else if (bid < TOPK_BLOCKS + CONV_BLOCKS) {
        // ---- x -> bf16 ----
        const int i = ((bid - TOPK_BLOCKS) * 256 + tid) * 4;
        const float4 v = *reinterpret_cast<const float4*>(x + i);
        ushort4 o;
        o.x = f2b(v.x); o.y = f2b(v.y); o.z = f2b(v.z); o.w = f2b(v.w);
        *reinterpret_cast<ushort4*>(xb + i) = o;
    } else {
        // ---- pack Wt[n][k] = W*[k][n'] bf16 ----
        const int n = bid - TOPK_BLOCKS - CONV_BLOCKS;
        const float* W; int nn;
        if (n < 512)       { W = Wq; nn = n; }
        else if (n < 1024) { W = Wk; nn = n - 512; }
        else if (n < 1536) { W = Wv; nn = n - 1024; }
        else               { W = Wo; nn = n - 1536; }
        for (int k = tid; k < 512; k += 256)
            Wt[(size_t)n * 512 + k] = f2b(W[(size_t)k * 512 + nn]);
        if (tid == 0 && n < 1536) {
            const float* bsel = (n < 512) ? bq : (n < 1024) ? bk : bv;
            bqkv[n] = bsel[nn];
        }
    }
}

// ---------------------------------------------------------------------------
// bf16 MFMA GEMM: C[m][n] = sum_k A[m][k] * Bt[n][k] + bias[n]
// 128x128 tile, 4 waves 2x2, BK=32, global_load_lds width-16 staging.
// ---------------------------------------------------------------------------
template <bool OUT_BF16>
__global__ __launch_bounds__(256) void gemm_mfma_kernel(
    const unsigned short* __restrict__ A,
    const unsigned short* __restrict__ Bt,
    const float* __restrict__ bias,
    void* __restrict__ Cv, int ldc)
{
    constexpr int K = 512;
    __shared__ __align__(16) unsigned short As[128 * 32];
    __shared__ __align__(16) unsigned short Bs[128 * 32];

    const int tid = threadIdx.x;
    const int m0 = blockIdx.x * 128;
    const int n0 = blockIdx.y * 128;
    const int wid = tid >> 6;
    const int lane = tid & 63;
    const int wm = (wid >> 1) * 64;
    const int wn = (wid & 1) * 64;
    const int l15 = lane & 15;
    const int kg = lane >> 4;

    const int srow = tid >> 2;
    const int sk = (tid & 3) * 8;

    f32x4 acc[4][4] = {};

    for (int kt = 0; kt < K; kt += 32) {
        #pragma unroll
        for (int c = 0; c < 2; ++c) {
            const unsigned short* ga = A + (size_t)(m0 + c * 64 + srow) * K + kt + sk;
            __builtin_amdgcn_global_load_lds(
                (const __attribute__((address_space(1))) void*)ga,
                (__attribute__((address_space(3))) void*)(&As[c * 2048 + tid * 8]),
                16, 0, 0);
            const unsigned short* gb = Bt + (size_t)(n0 + c * 64 + srow) * K + kt + sk;
            __builtin_amdgcn_global_load_lds(
                (const __attribute__((address_space(1))) void*)gb,
                (__attribute__((address_space(3))) void*)(&Bs[c * 2048 + tid * 8]),
                16, 0, 0);
        }
        __syncthreads();

        bf16x8 af[4], bfr[4];
        #pragma unroll
        for (int i = 0; i < 4; ++i) {
            af[i]  = *reinterpret_cast<const bf16x8*>(&As[(wm + i * 16 + l15) * 32 + kg * 8]);
            bfr[i] = *reinterpret_cast<const bf16x8*>(&Bs[(wn + i * 16 + l15) * 32 + kg * 8]);
        }
        #pragma unroll
        for (int i = 0; i < 4; ++i)
            #pragma unroll
            for (int j = 0; j < 4; ++j)
                acc[i][j] = __builtin_amdgcn_mfma_f32_16x16x32_bf16(af[i], bfr[j], acc[i][j], 0, 0, 0);
        __syncthreads();
    }

    // C/D layout (m89-verified): col = lane&15, row = (lane>>4)*4 + reg
    const int crow = kg * 4;
    #pragma unroll
    for (int i = 0; i < 4; ++i) {
        #pragma unroll
        for (int j = 0; j < 4; ++j) {
            const int col = n0 + wn + j * 16 + l15;
            const float bb = bias[col];
            #pragma unroll
            for (int r = 0; r < 4; ++r) {
                const int row = m0 + wm + i * 16 + crow + r;
                const float v = acc[i][j][r] + bb;
                if (OUT_BF16)
                    ((unsigned short*)Cv)[(size_t)row * ldc + col] = f2b(v);
                else
                    ((float*)Cv)[(size_t)row * ldc + col] = v;
            }
        }
    }
}

// ---------------------------------------------------------------------------
// Sparse attention. One 512-thread block per row; wave h = head h; waves
// fully independent (no block barrier). All neighbor/V addressing is scalar
// (SGPR base + lane voffset): zero VALU address math in the V path.
// qkv: [M][1536] bf16 = [Q512 | K512 | V512].
// ---------------------------------------------------------------------------
__global__ __launch_bounds__(512) void attn_kernel(
    const unsigned short* __restrict__ qkv,
    const int* __restrict__ nbr_idx,
    const int* __restrict__ nbr_cnt,
    unsigned short* __restrict__ ao)
{
    const int row = blockIdx.x;
    const int b = (row >= S_LEN) ? 1 : 0;
    const int tid = threadIdx.x;
    const int lane = tid & 63;
    const int h = __builtin_amdgcn_readfirstlane(tid >> 6);
    const int j = lane & 31;
    const int half = lane >> 5;

    __shared__ float sQ[N_HEADS][DH];

    const int cnt = __builtin_amdgcn_readfirstlane(nbr_cnt[row]);
    const int* nrow = nbr_idx + (size_t)row * KMAX;
    const unsigned short* qkvb_ = qkv + (size_t)b * S_LEN * 1536;

    // --- K gather (issued first): lane pair (j, j+32) splits the 64-dim dot ---
    int tj = nrow[j];
    tj = (j < cnt) ? tj : 0;
    const uint4* kp = reinterpret_cast<const uint4*>(
        qkvb_ + (size_t)tj * 1536 + 512 + h * DH + half * 32);
    uint4 ku[4];
    #pragma unroll
    for (int c = 0; c < 4; ++c) ku[c] = kp[c];

    // --- neighbor list into SGPRs ---
    int nbrs[KMAX];
    {
        const int4* n4 = reinterpret_cast<const int4*>(nrow);
        #pragma unroll
        for (int c = 0; c < 8; ++c) {
            const int4 v = n4[c];
            nbrs[c * 4 + 0] = __builtin_amdgcn_readfirstlane(v.x);
            nbrs[c * 4 + 1] = __builtin_amdgcn_readfirstlane(v.y);
            nbrs[c * 4 + 2] = __builtin_amdgcn_readfirstlane(v.z);
            nbrs[c * 4 + 3] = __builtin_amdgcn_readfirstlane(v.w);
        }
    }

    // --- V prefetch: scalar base per neighbor + shared lane voffset ---
    const unsigned short* vb_ = qkvb_ + 1024 + h * DH;
    unsigned int vr[KMAX];
    #pragma unroll
    for (int jj = 0; jj < KMAX; ++jj) {
        const int ts = (jj < cnt) ? nbrs[jj] : 0;          // uniform select
        vr[jj] = vb_[(size_t)ts * 1536 + lane];            // saddr + voffset
    }

    // --- Q share (intra-wave LDS; compiler orders ds_write -> ds_read) ---
    sQ[h][lane] = b2f(qkv[(size_t)row * 1536 + h * DH + lane]);

    // --- score: 64-dim dot split across lane halves ---
    const float* qp = &sQ[h][half * 32];
    float partial = 0.f;
    #pragma unroll
    for (int c = 0; c < 4; ++c) {
        const int d0 = c * 8;
        partial += qp[d0 + 0] * b2f(ku[c].x) + qp[d0 + 1] * b2f(ku[c].x >> 16)
                 + qp[d0 + 2] * b2f(ku[c].y) + qp[d0 + 3] * b2f(ku[c].y >> 16)
                 + qp[d0 + 4] * b2f(ku[c].z) + qp[d0 + 5] * b2f(ku[c].z >> 16)
                 + qp[d0 + 6] * b2f(ku[c].w) + qp[d0 + 7] * b2f(ku[c].w >> 16);
    }
    partial += __shfl_down(partial, 32, 64);   // lanes 0..31 hold full dots

    // --- softmax over lanes 0..31 ---
    const float sc = (half == 0 && j < cnt) ? partial * 0.125f : -INFINITY;
    float mx = sc;
    #pragma unroll
    for (int off = 16; off; off >>= 1) mx = fmaxf(mx, __shfl_xor(mx, off, 64));
    const float p = (half == 0 && j < cnt) ? expf(sc - mx) : 0.f;
    float sum = p;
    #pragma unroll
    for (int off = 16; off; off >>= 1) sum += __shfl_xor(sum, off, 64);
    const float inv = __uint_as_float(
        __builtin_amdgcn_readfirstlane(__float_as_uint(1.f / sum)));

    // --- PV: weights broadcast via readlane, 4 accumulators ---
    float o0 = 0.f, o1 = 0.f, o2 = 0.f, o3 = 0.f;
    #pragma unroll
    for (int jj = 0; jj < KMAX; jj += 4) {
        const float w0 = __uint_as_float(__builtin_amdgcn_readlane(__float_as_uint(p), jj));
        const float w1 = __uint_as_float(__builtin_amdgcn_readlane(__float_as_uint(p), jj + 1));
        const float w2 = __uint_as_float(__builtin_amdgcn_readlane(__float_as_uint(p), jj + 2));
        const float w3 = __uint_as_float(__builtin_amdgcn_readlane(__float_as_uint(p), jj + 3));
        o0 += w0 * b2f(vr[jj]);
        o1 += w1 * b2f(vr[jj + 1]);
        o2 += w2 * b2f(vr[jj + 2]);
        o3 += w3 * b2f(vr[jj + 3]);
    }
    const float o = ((o0 + o1) + (o2 + o3)) * inv;
    ao[(size_t)row * D_MODEL + h * DH + lane] = f2b(o);
}

// ---------------------------------------------------------------------------
extern "C" void kernel_launch(void* const* d_in, const int* in_sizes, int n_in,
                              void* d_out, int out_size, void* d_ws, size_t ws_size,
                              hipStream_t stream) {
    const float* x   = (const float*)d_in[0];
    const float* pos = (const float*)d_in[1];
    const float* Wq  = (const float*)d_in[2];
    const float* bq  = (const float*)d_in[3];
    const float* Wk  = (const float*)d_in[4];
    const float* bk  = (const float*)d_in[5];
    const float* Wv  = (const float*)d_in[6];
    const float* bv  = (const float*)d_in[7];
    const float* Wo  = (const float*)d_in[8];
    const float* bo  = (const float*)d_in[9];
    float* out = (float*)d_out;

    // workspace layout (all 16B-aligned)
    unsigned short* xb   = (unsigned short*)d_ws;                 // 6144*512
    unsigned short* Wt   = xb + (size_t)M_ROWS * 512;             // 2048*512
    float*          bqkv = (float*)(Wt + (size_t)2048 * 512);     // 1536
    unsigned short* qkvb = (unsigned short*)(bqkv + 1536);        // 6144*1536
    unsigned short* aob  = qkvb + (size_t)M_ROWS * 1536;          // 6144*512
    int*            nidx = (int*)(aob + (size_t)M_ROWS * 512);    // 6144*32
    int*            ncnt = nidx + (size_t)M_ROWS * KMAX;          // 6144

    prep_kernel<<<TOPK_BLOCKS + CONV_BLOCKS + PACK_BLOCKS, 256, 0, stream>>>(
        x, pos, Wq, bq, Wk, bk, Wv, bv, Wo, xb, Wt, bqkv, nidx, ncnt);

    dim3 g1(M_ROWS / 128, 1536 / 128);
    gemm_mfma_kernel<true><<<g1, 256, 0, stream>>>(xb, Wt, bqkv, qkvb, 1536);

    attn_kernel<<<M_ROWS, 512, 0, stream>>>(qkvb, nidx, ncnt, aob);

    dim3 g2(M_ROWS / 128, 512 / 128);
    gemm_mfma_kernel<false><<<g2, 256, 0, stream>>>(aob, Wt + (size_t)1536 * 512, bo, out, 512);
}

// Round 7
// 86.713 us; speedup vs baseline: 1.5465x; 1.1708x over previous
//
#include <hip/hip_runtime.h>
#include <math.h>

#define D_MODEL 512
#define N_HEADS 8
#define DH      64
#define S_LEN   3072
#define BATCH   2
#define KMAX    32
#define M_ROWS  6144
#define CAND_CAP 512

#define TOPK_BLOCKS (M_ROWS / 4)                 // 1536 (4 rows per block)
#define CONV_BLOCKS (M_ROWS * D_MODEL / 1024)    // 3072
#define PACK_BLOCKS 2048

typedef __attribute__((ext_vector_type(8))) short bf16x8;
typedef __attribute__((ext_vector_type(4))) float f32x4;
typedef __attribute__((ext_vector_type(2))) short s16x2;
typedef unsigned long long u64;

__device__ __forceinline__ float b2f(unsigned int u) {
    return __uint_as_float((u & 0xFFFFu) << 16);
}
__device__ __forceinline__ unsigned short f2b(float f) {
    unsigned int u = __float_as_uint(f);
    return (unsigned short)((u + 0x7FFFu + ((u >> 16) & 1u)) >> 16);  // RNE
}

#if __has_builtin(__builtin_amdgcn_fdot2_f32_bf16)
#define HAS_DOT2 1
__device__ __forceinline__ float dot2bf(unsigned int a, unsigned int b, float c) {
    return __builtin_amdgcn_fdot2_f32_bf16(
        __builtin_bit_cast(s16x2, a), __builtin_bit_cast(s16x2, b), c, false);
}
#else
#define HAS_DOT2 0
__device__ __forceinline__ float dot2bf(unsigned int a, unsigned int b, float c) {
    return c + b2f(a) * b2f(b) + b2f(a >> 16) * b2f(b >> 16);
}
#endif

// ---------------------------------------------------------------------------
// prep: fused topk (4 rows/block) | x->bf16 | weight transpose+pack.
// ---------------------------------------------------------------------------
__global__ __launch_bounds__(256) void prep_kernel(
    const float* __restrict__ x, const float* __restrict__ pos,
    const float* __restrict__ Wq, const float* __restrict__ bq,
    const float* __restrict__ Wk, const float* __restrict__ bk,
    const float* __restrict__ Wv, const float* __restrict__ bv,
    const float* __restrict__ Wo,
    unsigned short* __restrict__ xb, unsigned short* __restrict__ Wt,
    float* __restrict__ bqkv,
    int* __restrict__ nbr_idx, int* __restrict__ nbr_cnt)
{
    const int bid = blockIdx.x;
    const int tid = threadIdx.x;

    if (bid < TOPK_BLOCKS) {
        __shared__ u64 s_keys[4][CAND_CAP];
        __shared__ int s_n[4];
        const int r0 = bid * 4;
        const int b = (r0 >= S_LEN) ? 1 : 0;
        if (tid < 4) s_n[tid] = 0;
        __syncthreads();

        float qx[4], qy[4], qz[4];
        #pragma unroll
        for (int r = 0; r < 4; ++r) {
            qx[r] = pos[(size_t)(r0 + r) * 3 + 0];
            qy[r] = pos[(size_t)(r0 + r) * 3 + 1];
            qz[r] = pos[(size_t)(r0 + r) * 3 + 2];
        }
        const float* pb = pos + (size_t)b * S_LEN * 3;
        #pragma unroll
        for (int i = 0; i < 12; ++i) {
            const int t = tid + i * 256;
            const float x3 = pb[t * 3 + 0], y3 = pb[t * 3 + 1], z3 = pb[t * 3 + 2];
            #pragma unroll
            for (int r = 0; r < 4; ++r) {
                const float dx = qx[r] - x3, dy = qy[r] - y3, dz = qz[r] - z3;
                const float d2 = dx * dx + dy * dy + dz * dz;
                if (d2 < 0.25f) {
                    const int slot = atomicAdd(&s_n[r], 1);
                    if (slot < CAND_CAP)
                        s_keys[r][slot] = ((u64)__float_as_uint(d2) << 32) | (unsigned)t;
                }
            }
        }
        __syncthreads();

        const int rr = tid >> 6, c0 = tid & 63;
        const int n = min(s_n[rr], CAND_CAP);
        for (int c = c0; c < n; c += 64) {
            const u64 k = s_keys[rr][c];
            int rank = 0;
            for (int j = 0; j < n; ++j) rank += (s_keys[rr][j] < k) ? 1 : 0;
            if (rank < KMAX)
                nbr_idx[(size_t)(r0 + rr) * KMAX + rank] = (int)(k & 0xFFFFFFFFu);
        }
        if (c0 == 0) nbr_cnt[r0 + rr] = min(n, KMAX);
    } else if (bid < TOPK_BLOCKS + CONV_BLOCKS) {
        const int i = ((bid - TOPK_BLOCKS) * 256 + tid) * 4;
        const float4 v = *reinterpret_cast<const float4*>(x + i);
        ushort4 o;
        o.x = f2b(v.x); o.y = f2b(v.y); o.z = f2b(v.z); o.w = f2b(v.w);
        *reinterpret_cast<ushort4*>(xb + i) = o;
    } else {
        const int n = bid - TOPK_BLOCKS - CONV_BLOCKS;
        const float* W; int nn;
        if (n < 512)       { W = Wq; nn = n; }
        else if (n < 1024) { W = Wk; nn = n - 512; }
        else if (n < 1536) { W = Wv; nn = n - 1024; }
        else               { W = Wo; nn = n - 1536; }
        for (int k = tid; k < 512; k += 256)
            Wt[(size_t)n * 512 + k] = f2b(W[(size_t)k * 512 + nn]);
        if (tid == 0 && n < 1536) {
            const float* bsel = (n < 512) ? bq : (n < 1024) ? bk : bv;
            bqkv[n] = bsel[nn];
        }
    }
}

// ---------------------------------------------------------------------------
// bf16 MFMA GEMM: C[m][n] = sum_k A[m][k] * Bt[n][k] + bias[n]
// 128x128 tile, 4 waves 2x2, BK=32, global_load_lds width-16 staging.
// ---------------------------------------------------------------------------
template <bool OUT_BF16>
__global__ __launch_bounds__(256) void gemm_mfma_kernel(
    const unsigned short* __restrict__ A,
    const unsigned short* __restrict__ Bt,
    const float* __restrict__ bias,
    void* __restrict__ Cv, int ldc)
{
    constexpr int K = 512;
    __shared__ __align__(16) unsigned short As[128 * 32];
    __shared__ __align__(16) unsigned short Bs[128 * 32];

    const int tid = threadIdx.x;
    const int m0 = blockIdx.x * 128;
    const int n0 = blockIdx.y * 128;
    const int wid = tid >> 6;
    const int lane = tid & 63;
    const int wm = (wid >> 1) * 64;
    const int wn = (wid & 1) * 64;
    const int l15 = lane & 15;
    const int kg = lane >> 4;

    const int srow = tid >> 2;
    const int sk = (tid & 3) * 8;

    f32x4 acc[4][4] = {};

    for (int kt = 0; kt < K; kt += 32) {
        #pragma unroll
        for (int c = 0; c < 2; ++c) {
            const unsigned short* ga = A + (size_t)(m0 + c * 64 + srow) * K + kt + sk;
            __builtin_amdgcn_global_load_lds(
                (const __attribute__((address_space(1))) void*)ga,
                (__attribute__((address_space(3))) void*)(&As[c * 2048 + tid * 8]),
                16, 0, 0);
            const unsigned short* gb = Bt + (size_t)(n0 + c * 64 + srow) * K + kt + sk;
            __builtin_amdgcn_global_load_lds(
                (const __attribute__((address_space(1))) void*)gb,
                (__attribute__((address_space(3))) void*)(&Bs[c * 2048 + tid * 8]),
                16, 0, 0);
        }
        __syncthreads();

        bf16x8 af[4], bfr[4];
        #pragma unroll
        for (int i = 0; i < 4; ++i) {
            af[i]  = *reinterpret_cast<const bf16x8*>(&As[(wm + i * 16 + l15) * 32 + kg * 8]);
            bfr[i] = *reinterpret_cast<const bf16x8*>(&Bs[(wn + i * 16 + l15) * 32 + kg * 8]);
        }
        #pragma unroll
        for (int i = 0; i < 4; ++i)
            #pragma unroll
            for (int j = 0; j < 4; ++j)
                acc[i][j] = __builtin_amdgcn_mfma_f32_16x16x32_bf16(af[i], bfr[j], acc[i][j], 0, 0, 0);
        __syncthreads();
    }

    const int crow = kg * 4;
    #pragma unroll
    for (int i = 0; i < 4; ++i) {
        #pragma unroll
        for (int j = 0; j < 4; ++j) {
            const int col = n0 + wn + j * 16 + l15;
            const float bb = bias[col];
            #pragma unroll
            for (int r = 0; r < 4; ++r) {
                const int row = m0 + wm + i * 16 + crow + r;
                const float v = acc[i][j][r] + bb;
                if (OUT_BF16)
                    ((unsigned short*)Cv)[(size_t)row * ldc + col] = f2b(v);
                else
                    ((float*)Cv)[(size_t)row * ldc + col] = v;
            }
        }
    }
}

// ---------------------------------------------------------------------------
// Sparse attention. Block = row (512 thr); wave h = head h. No barriers:
// each wave stages its own packed-Q and its own copy of the neighbor byte
// offsets (benign duplicate LDS writes). Score and PV consume packed bf16
// via v_dot2_f32_bf16 (fallback: manual unpack).
// qkv: [M][1536] bf16 = [Q512 | K512 | V512], 3072 B per row.
// ---------------------------------------------------------------------------
__global__ __launch_bounds__(512) void attn_kernel(
    const unsigned short* __restrict__ qkv,
    const int* __restrict__ nbr_idx,
    const int* __restrict__ nbr_cnt,
    unsigned short* __restrict__ ao)
{
    const int row = blockIdx.x;
    const int b = (row >= S_LEN) ? 1 : 0;
    const int tid = threadIdx.x;
    const int h = tid >> 6;
    const int lane = tid & 63;
    const int j = lane & 31;
    const int half = lane >> 5;

    __shared__ unsigned int s_off[KMAX];        // clamped neighbor byte offsets
    __shared__ unsigned int sQ[N_HEADS][32];    // packed bf16 Q, per head

    const int cnt = nbr_cnt[row];

    // Wave-local staging: lanes 0..31 pack Q, lanes 32..63 build offsets.
    if (lane < 32) {
        sQ[h][lane] = ((const unsigned int*)(qkv + (size_t)row * 1536 + h * DH))[lane];
    } else {
        const int j2 = lane - 32;
        int t = nbr_idx[(size_t)row * KMAX + j2];
        t = (j2 < cnt) ? t : 0;
        s_off[j2] = (unsigned int)t * 3072u;    // bytes per qkv row
    }

    const char* qkvb_ = (const char*)(qkv + (size_t)b * S_LEN * 1536);

    // --- K gather: lane (half, j) loads 32 dims of neighbor j's K ---
    const unsigned int offj = s_off[j];
    const char* krow = qkvb_ + offj + 1024 + h * 128 + half * 64;
    uint4 ku[4];
    #pragma unroll
    for (int c = 0; c < 4; ++c) ku[c] = ((const uint4*)krow)[c];

    // --- V prefetch: per-lane base + uniform LDS offset per neighbor ---
    const char* vbase_l = qkvb_ + 2048 + h * 128 + lane * 2;
    unsigned int vr[KMAX];
    #pragma unroll
    for (int jj = 0; jj < KMAX; ++jj)
        vr[jj] = *(const unsigned short*)(vbase_l + s_off[jj]);

    // --- score: 32 dims per lane via packed dot2 ---
    const unsigned int* qws = &sQ[h][half * 16];
    unsigned int kw[16];
    #pragma unroll
    for (int c = 0; c < 4; ++c) {
        kw[c * 4 + 0] = ku[c].x; kw[c * 4 + 1] = ku[c].y;
        kw[c * 4 + 2] = ku[c].z; kw[c * 4 + 3] = ku[c].w;
    }
    float partial = 0.f;
    #pragma unroll
    for (int c = 0; c < 16; ++c) partial = dot2bf(kw[c], qws[c], partial);
    partial += __shfl_down(partial, 32, 64);   // lanes 0..31 hold full dots

    // --- softmax over lanes 0..31 ---
    const float sc = (half == 0 && j < cnt) ? partial * 0.125f : -INFINITY;
    float mx = sc;
    #pragma unroll
    for (int off = 16; off; off >>= 1) mx = fmaxf(mx, __shfl_xor(mx, off, 64));
    const float p = (half == 0 && j < cnt) ? expf(sc - mx) : 0.f;
    float sum = p;
    #pragma unroll
    for (int off = 16; off; off >>= 1) sum += __shfl_xor(sum, off, 64);
    const float inv = __uint_as_float(
        __builtin_amdgcn_readfirstlane(__float_as_uint(1.f / sum)));

    // --- weights -> packed bf16 pairs (even lanes hold (p_2i, p_2i+1)) ---
    const float pn = __shfl_xor(p, 1, 64);
    const unsigned int pw = ((unsigned int)f2b(pn) << 16) | f2b(p);

    // --- PV: per 2 neighbors: 1 readlane + 1 pack + 1 dot2 ---
    float o0 = 0.f, o1 = 0.f;
    #pragma unroll
    for (int i = 0; i < 16; i += 2) {
        const unsigned int w0 = __builtin_amdgcn_readlane(pw, 2 * i);
        const unsigned int w1 = __builtin_amdgcn_readlane(pw, 2 * i + 2);
        const unsigned int vp0 = (vr[2 * i + 1] << 16) | vr[2 * i];
        const unsigned int vp1 = (vr[2 * i + 3] << 16) | vr[2 * i + 2];
        o0 = dot2bf(vp0, w0, o0);
        o1 = dot2bf(vp1, w1, o1);
    }
    const float o = (o0 + o1) * inv;
    ao[(size_t)row * D_MODEL + h * DH + lane] = f2b(o);
}

// ---------------------------------------------------------------------------
extern "C" void kernel_launch(void* const* d_in, const int* in_sizes, int n_in,
                              void* d_out, int out_size, void* d_ws, size_t ws_size,
                              hipStream_t stream) {
    const float* x   = (const float*)d_in[0];
    const float* pos = (const float*)d_in[1];
    const float* Wq  = (const float*)d_in[2];
    const float* bq  = (const float*)d_in[3];
    const float* Wk  = (const float*)d_in[4];
    const float* bk  = (const float*)d_in[5];
    const float* Wv  = (const float*)d_in[6];
    const float* bv  = (const float*)d_in[7];
    const float* Wo  = (const float*)d_in[8];
    const float* bo  = (const float*)d_in[9];
    float* out = (float*)d_out;

    unsigned short* xb   = (unsigned short*)d_ws;                 // 6144*512
    unsigned short* Wt   = xb + (size_t)M_ROWS * 512;             // 2048*512
    float*          bqkv = (float*)(Wt + (size_t)2048 * 512);     // 1536
    unsigned short* qkvb = (unsigned short*)(bqkv + 1536);        // 6144*1536
    unsigned short* aob  = qkvb + (size_t)M_ROWS * 1536;          // 6144*512
    int*            nidx = (int*)(aob + (size_t)M_ROWS * 512);    // 6144*32
    int*            ncnt = nidx + (size_t)M_ROWS * KMAX;          // 6144

    prep_kernel<<<TOPK_BLOCKS + CONV_BLOCKS + PACK_BLOCKS, 256, 0, stream>>>(
        x, pos, Wq, bq, Wk, bk, Wv, bv, Wo, xb, Wt, bqkv, nidx, ncnt);

    dim3 g1(M_ROWS / 128, 1536 / 128);
    gemm_mfma_kernel<true><<<g1, 256, 0, stream>>>(xb, Wt, bqkv, qkvb, 1536);

    attn_kernel<<<M_ROWS, 512, 0, stream>>>(qkvb, nidx, ncnt, aob);

    dim3 g2(M_ROWS / 128, 512 / 128);
    gemm_mfma_kernel<false><<<g2, 256, 0, stream>>>(aob, Wt + (size_t)1536 * 512, bo, out, 512);
}

// Round 8
// 81.466 us; speedup vs baseline: 1.6461x; 1.0644x over previous
//
#include <hip/hip_runtime.h>
#include <math.h>

#define D_MODEL 512
#define N_HEADS 8
#define DH      64
#define S_LEN   3072
#define BATCH   2
#define KMAX    32
#define M_ROWS  6144
#define CAND_CAP 512

#define TOPK_BLOCKS (M_ROWS / 4)                 // 1536 (4 rows per block)
#define CONV_BLOCKS (M_ROWS * D_MODEL / 1024)    // 3072
#define PACK_BLOCKS 2048

typedef __attribute__((ext_vector_type(8))) short bf16x8;
typedef __attribute__((ext_vector_type(4))) float f32x4;
typedef __attribute__((ext_vector_type(2))) short s16x2;
typedef unsigned long long u64;

__device__ __forceinline__ float b2f(unsigned int u) {
    return __uint_as_float((u & 0xFFFFu) << 16);
}
__device__ __forceinline__ unsigned short f2b(float f) {
    unsigned int u = __float_as_uint(f);
    return (unsigned short)((u + 0x7FFFu + ((u >> 16) & 1u)) >> 16);  // RNE
}

#if __has_builtin(__builtin_amdgcn_fdot2_f32_bf16)
__device__ __forceinline__ float dot2bf(unsigned int a, unsigned int b, float c) {
    return __builtin_amdgcn_fdot2_f32_bf16(
        __builtin_bit_cast(s16x2, a), __builtin_bit_cast(s16x2, b), c, false);
}
#else
__device__ __forceinline__ float dot2bf(unsigned int a, unsigned int b, float c) {
    return c + b2f(a) * b2f(b) + b2f(a >> 16) * b2f(b >> 16);
}
#endif

// ---------------------------------------------------------------------------
// prep: fused topk (4 rows/block) | x->bf16 | weight transpose+pack.
// ---------------------------------------------------------------------------
__global__ __launch_bounds__(256) void prep_kernel(
    const float* __restrict__ x, const float* __restrict__ pos,
    const float* __restrict__ Wq, const float* __restrict__ bq,
    const float* __restrict__ Wk, const float* __restrict__ bk,
    const float* __restrict__ Wv, const float* __restrict__ bv,
    const float* __restrict__ Wo,
    unsigned short* __restrict__ xb, unsigned short* __restrict__ Wt,
    float* __restrict__ bqkv,
    int* __restrict__ nbr_idx, int* __restrict__ nbr_cnt)
{
    const int bid = blockIdx.x;
    const int tid = threadIdx.x;

    if (bid < TOPK_BLOCKS) {
        __shared__ u64 s_keys[4][CAND_CAP];
        __shared__ int s_n[4];
        const int r0 = bid * 4;
        const int b = (r0 >= S_LEN) ? 1 : 0;
        if (tid < 4) s_n[tid] = 0;
        __syncthreads();

        float qx[4], qy[4], qz[4];
        #pragma unroll
        for (int r = 0; r < 4; ++r) {
            qx[r] = pos[(size_t)(r0 + r) * 3 + 0];
            qy[r] = pos[(size_t)(r0 + r) * 3 + 1];
            qz[r] = pos[(size_t)(r0 + r) * 3 + 2];
        }
        const float* pb = pos + (size_t)b * S_LEN * 3;
        #pragma unroll
        for (int i = 0; i < 12; ++i) {
            const int t = tid + i * 256;
            const float x3 = pb[t * 3 + 0], y3 = pb[t * 3 + 1], z3 = pb[t * 3 + 2];
            #pragma unroll
            for (int r = 0; r < 4; ++r) {
                const float dx = qx[r] - x3, dy = qy[r] - y3, dz = qz[r] - z3;
                const float d2 = dx * dx + dy * dy + dz * dz;
                if (d2 < 0.25f) {
                    const int slot = atomicAdd(&s_n[r], 1);
                    if (slot < CAND_CAP)
                        s_keys[r][slot] = ((u64)__float_as_uint(d2) << 32) | (unsigned)t;
                }
            }
        }
        __syncthreads();

        const int rr = tid >> 6, c0 = tid & 63;
        const int n = min(s_n[rr], CAND_CAP);
        for (int c = c0; c < n; c += 64) {
            const u64 k = s_keys[rr][c];
            int rank = 0;
            for (int j = 0; j < n; ++j) rank += (s_keys[rr][j] < k) ? 1 : 0;
            if (rank < KMAX)
                nbr_idx[(size_t)(r0 + rr) * KMAX + rank] = (int)(k & 0xFFFFFFFFu);
        }
        if (c0 == 0) nbr_cnt[r0 + rr] = min(n, KMAX);
    } else if (bid < TOPK_BLOCKS + CONV_BLOCKS) {
        const int i = ((bid - TOPK_BLOCKS) * 256 + tid) * 4;
        const float4 v = *reinterpret_cast<const float4*>(x + i);
        ushort4 o;
        o.x = f2b(v.x); o.y = f2b(v.y); o.z = f2b(v.z); o.w = f2b(v.w);
        *reinterpret_cast<ushort4*>(xb + i) = o;
    } else {
        const int n = bid - TOPK_BLOCKS - CONV_BLOCKS;
        const float* W; int nn;
        if (n < 512)       { W = Wq; nn = n; }
        else if (n < 1024) { W = Wk; nn = n - 512; }
        else if (n < 1536) { W = Wv; nn = n - 1024; }
        else               { W = Wo; nn = n - 1536; }
        for (int k = tid; k < 512; k += 256)
            Wt[(size_t)n * 512 + k] = f2b(W[(size_t)k * 512 + nn]);
        if (tid == 0 && n < 1536) {
            const float* bsel = (n < 512) ? bq : (n < 1024) ? bk : bv;
            bqkv[n] = bsel[nn];
        }
    }
}

// ---------------------------------------------------------------------------
// bf16 MFMA GEMM: C[m][n] = sum_k A[m][k] * Bt[n][k] + bias[n]
// 128x128 tile, 4 waves 2x2, BK=32, global_load_lds width-16 staging.
// ---------------------------------------------------------------------------
template <bool OUT_BF16>
__global__ __launch_bounds__(256) void gemm_mfma_kernel(
    const unsigned short* __restrict__ A,
    const unsigned short* __restrict__ Bt,
    const float* __restrict__ bias,
    void* __restrict__ Cv, int ldc)
{
    constexpr int K = 512;
    __shared__ __align__(16) unsigned short As[128 * 32];
    __shared__ __align__(16) unsigned short Bs[128 * 32];

    const int tid = threadIdx.x;
    const int m0 = blockIdx.x * 128;
    const int n0 = blockIdx.y * 128;
    const int wid = tid >> 6;
    const int lane = tid & 63;
    const int wm = (wid >> 1) * 64;
    const int wn = (wid & 1) * 64;
    const int l15 = lane & 15;
    const int kg = lane >> 4;

    const int srow = tid >> 2;
    const int sk = (tid & 3) * 8;

    f32x4 acc[4][4] = {};

    for (int kt = 0; kt < K; kt += 32) {
        #pragma unroll
        for (int c = 0; c < 2; ++c) {
            const unsigned short* ga = A + (size_t)(m0 + c * 64 + srow) * K + kt + sk;
            __builtin_amdgcn_global_load_lds(
                (const __attribute__((address_space(1))) void*)ga,
                (__attribute__((address_space(3))) void*)(&As[c * 2048 + tid * 8]),
                16, 0, 0);
            const unsigned short* gb = Bt + (size_t)(n0 + c * 64 + srow) * K + kt + sk;
            __builtin_amdgcn_global_load_lds(
                (const __attribute__((address_space(1))) void*)gb,
                (__attribute__((address_space(3))) void*)(&Bs[c * 2048 + tid * 8]),
                16, 0, 0);
        }
        __syncthreads();

        bf16x8 af[4], bfr[4];
        #pragma unroll
        for (int i = 0; i < 4; ++i) {
            af[i]  = *reinterpret_cast<const bf16x8*>(&As[(wm + i * 16 + l15) * 32 + kg * 8]);
            bfr[i] = *reinterpret_cast<const bf16x8*>(&Bs[(wn + i * 16 + l15) * 32 + kg * 8]);
        }
        #pragma unroll
        for (int i = 0; i < 4; ++i)
            #pragma unroll
            for (int j = 0; j < 4; ++j)
                acc[i][j] = __builtin_amdgcn_mfma_f32_16x16x32_bf16(af[i], bfr[j], acc[i][j], 0, 0, 0);
        __syncthreads();
    }

    const int crow = kg * 4;
    #pragma unroll
    for (int i = 0; i < 4; ++i) {
        #pragma unroll
        for (int j = 0; j < 4; ++j) {
            const int col = n0 + wn + j * 16 + l15;
            const float bb = bias[col];
            #pragma unroll
            for (int r = 0; r < 4; ++r) {
                const int row = m0 + wm + i * 16 + crow + r;
                const float v = acc[i][j][r] + bb;
                if (OUT_BF16)
                    ((unsigned short*)Cv)[(size_t)row * ldc + col] = f2b(v);
                else
                    ((float*)Cv)[(size_t)row * ldc + col] = v;
            }
        }
    }
}

// ---------------------------------------------------------------------------
// Sparse attention. Block = row (512 thr, 8 waves = 8 heads).
// K rows staged into LDS via coalesced global_load_lds (1 instr = 1 KB row;
// kills the scattered-gather TA serialization). Row pitch 520 ushorts
// (1040 B): pad lives BETWEEN rows so each staging write stays contiguous,
// and the x65 pitch rotates bank groups by j&7 -> ds_read_b128 at the
// structural LDS minimum. V read from global, coalesced per neighbor,
// issued while K staging is in flight. Score/softmax/PV identical to R7.
// qkv: [M][1536] bf16 = [Q512 | K512 | V512], 3072 B per row.
// ---------------------------------------------------------------------------
__global__ __launch_bounds__(512) void attn_kernel(
    const unsigned short* __restrict__ qkv,
    const int* __restrict__ nbr_idx,
    const int* __restrict__ nbr_cnt,
    unsigned short* __restrict__ ao)
{
    const int row = blockIdx.x;
    const int b = (row >= S_LEN) ? 1 : 0;
    const int tid = threadIdx.x;
    const int h = tid >> 6;
    const int lane = tid & 63;
    const int j = lane & 31;
    const int half = lane >> 5;

    __shared__ __align__(16) unsigned short K_lds[KMAX][520];  // 33,280 B
    __shared__ unsigned int s_off[KMAX];
    __shared__ unsigned int sQ[N_HEADS][32];
    __shared__ int s_cnt;

    if (tid < KMAX) {
        const int cnt0 = nbr_cnt[row];
        int t = nbr_idx[(size_t)row * KMAX + tid];
        t = (tid < cnt0) ? t : 0;
        s_off[tid] = (unsigned int)t * 3072u;   // qkv row bytes
        if (tid == 0) s_cnt = cnt0;
    }
    if (lane < 32)   // packed bf16 Q per head
        sQ[h][lane] = ((const unsigned int*)(qkv + (size_t)row * 1536 + h * DH))[lane];
    __syncthreads();

    const int cnt = s_cnt;
    const char* qkvb_ = (const char*)qkv + (size_t)b * S_LEN * 3072;

    // --- K staging: wave h stages neighbor rows h*4..h*4+3 (1 KB each) ---
    {
        const int jb = h * 4;
        #pragma unroll
        for (int c = 0; c < 4; ++c) {
            const int jj = jb + c;
            const char* src = qkvb_ + s_off[jj] + 1024 + lane * 16;
            __builtin_amdgcn_global_load_lds(
                (const __attribute__((address_space(1))) void*)src,
                (__attribute__((address_space(3))) void*)(&K_lds[jj][0]),
                16, 0, 0);
        }
    }

    // --- V prefetch from global (coalesced 128 B per neighbor), in flight
    //     alongside the K staging ---
    const char* vbase_l = qkvb_ + 2048 + h * 128 + lane * 2;
    unsigned int vr[KMAX];
    #pragma unroll
    for (int jj = 0; jj < KMAX; ++jj)
        vr[jj] = *(const unsigned short*)(vbase_l + s_off[jj]);

    __syncthreads();   // drains vmcnt (staging + V) before LDS reads

    // --- score: lane (half, j) reads 32 dims of neighbor j's K from LDS ---
    const uint4* kp = reinterpret_cast<const uint4*>(&K_lds[j][h * 64 + half * 32]);
    uint4 ku[4];
    #pragma unroll
    for (int c = 0; c < 4; ++c) ku[c] = kp[c];

    const unsigned int* qws = &sQ[h][half * 16];
    float partial = 0.f;
    #pragma unroll
    for (int c = 0; c < 4; ++c) {
        partial = dot2bf(ku[c].x, qws[c * 4 + 0], partial);
        partial = dot2bf(ku[c].y, qws[c * 4 + 1], partial);
        partial = dot2bf(ku[c].z, qws[c * 4 + 2], partial);
        partial = dot2bf(ku[c].w, qws[c * 4 + 3], partial);
    }
    partial += __shfl_down(partial, 32, 64);   // lanes 0..31 hold full dots

    // --- softmax over lanes 0..31 ---
    const float sc = (half == 0 && j < cnt) ? partial * 0.125f : -INFINITY;
    float mx = sc;
    #pragma unroll
    for (int off = 16; off; off >>= 1) mx = fmaxf(mx, __shfl_xor(mx, off, 64));
    const float p = (half == 0 && j < cnt) ? expf(sc - mx) : 0.f;
    float sum = p;
    #pragma unroll
    for (int off = 16; off; off >>= 1) sum += __shfl_xor(sum, off, 64);
    const float inv = __uint_as_float(
        __builtin_amdgcn_readfirstlane(__float_as_uint(1.f / sum)));

    // --- weights -> packed bf16 pairs (even lanes hold (p_2i, p_2i+1)) ---
    const float pn = __shfl_xor(p, 1, 64);
    const unsigned int pw = ((unsigned int)f2b(pn) << 16) | f2b(p);

    // --- PV: per 2 neighbors: 1 readlane + 1 pack + 1 dot2 ---
    float o0 = 0.f, o1 = 0.f;
    #pragma unroll
    for (int i = 0; i < 16; i += 2) {
        const unsigned int w0 = __builtin_amdgcn_readlane(pw, 2 * i);
        const unsigned int w1 = __builtin_amdgcn_readlane(pw, 2 * i + 2);
        const unsigned int vp0 = (vr[2 * i + 1] << 16) | vr[2 * i];
        const unsigned int vp1 = (vr[2 * i + 3] << 16) | vr[2 * i + 2];
        o0 = dot2bf(vp0, w0, o0);
        o1 = dot2bf(vp1, w1, o1);
    }
    const float o = (o0 + o1) * inv;
    ao[(size_t)row * D_MODEL + h * DH + lane] = f2b(o);
}

// ---------------------------------------------------------------------------
extern "C" void kernel_launch(void* const* d_in, const int* in_sizes, int n_in,
                              void* d_out, int out_size, void* d_ws, size_t ws_size,
                              hipStream_t stream) {
    const float* x   = (const float*)d_in[0];
    const float* pos = (const float*)d_in[1];
    const float* Wq  = (const float*)d_in[2];
    const float* bq  = (const float*)d_in[3];
    const float* Wk  = (const float*)d_in[4];
    const float* bk  = (const float*)d_in[5];
    const float* Wv  = (const float*)d_in[6];
    const float* bv  = (const float*)d_in[7];
    const float* Wo  = (const float*)d_in[8];
    const float* bo  = (const float*)d_in[9];
    float* out = (float*)d_out;

    unsigned short* xb   = (unsigned short*)d_ws;                 // 6144*512
    unsigned short* Wt   = xb + (size_t)M_ROWS * 512;             // 2048*512
    float*          bqkv = (float*)(Wt + (size_t)2048 * 512);     // 1536
    unsigned short* qkvb = (unsigned short*)(bqkv + 1536);        // 6144*1536
    unsigned short* aob  = qkvb + (size_t)M_ROWS * 1536;          // 6144*512
    int*            nidx = (int*)(aob + (size_t)M_ROWS * 512);    // 6144*32
    int*            ncnt = nidx + (size_t)M_ROWS * KMAX;          // 6144

    prep_kernel<<<TOPK_BLOCKS + CONV_BLOCKS + PACK_BLOCKS, 256, 0, stream>>>(
        x, pos, Wq, bq, Wk, bk, Wv, bv, Wo, xb, Wt, bqkv, nidx, ncnt);

    dim3 g1(M_ROWS / 128, 1536 / 128);
    gemm_mfma_kernel<true><<<g1, 256, 0, stream>>>(xb, Wt, bqkv, qkvb, 1536);

    attn_kernel<<<M_ROWS, 512, 0, stream>>>(qkvb, nidx, ncnt, aob);

    dim3 g2(M_ROWS / 128, 512 / 128);
    gemm_mfma_kernel<false><<<g2, 256, 0, stream>>>(aob, Wt + (size_t)1536 * 512, bo, out, 512);
}